// Round 1
// baseline (203.601 us; speedup 1.0000x reference)
//
#include <hip/hip_runtime.h>
#include <cstdint>

#define MDIM 8192
#define NDIM 8192
#define QPR  (NDIM / 2)     // int32 entries (one packed byte each) per row = 4096
#define ABPR (NDIM / 64)    // absmax blocks per row = 128
#define ROWS_PER_BLOCK 16
#define NITER 64            // per row: 16 lanes x 4 int32 x 64 iters = 4096 int32

typedef _Float16 half2_t __attribute__((ext_vector_type(2)));

// fp4 bitsandbytes codebook entry -> IEEE f16 bits, pure VALU.
// magnitudes k=0..7: {0, 1/192, 2/3, 1, 1/3, 1/2, 1/6, 1/4}
// f16 hi-byte table (byte k): 0x00,0x1D,0x39,0x3C,0x35,0x38,0x31,0x34
// low mantissa byte is 0x55 exactly when hi-byte is odd; sign = idx bit3.
__device__ __forceinline__ uint32_t f16bits(uint32_t idx) {
  uint32_t k  = idx & 7u;
  uint32_t hb = (uint32_t)(0x343138353C391D00ull >> (k * 8)) & 0xFFu;
  uint32_t lb = (0u - (hb & 1u)) & 0x55u;
  return (hb << 8) | lb | ((idx & 8u) << 12);
}

// packed byte -> half2 (element0 = hi nibble = even column, element1 = lo nibble)
__device__ __forceinline__ uint32_t dec_pair(uint32_t b) {
  return f16bits((b >> 4) & 15u) | (f16bits(b & 15u) << 16);
}

__device__ __forceinline__ float fdot2(uint32_t w, uint32_t x, float c) {
#if __has_builtin(__builtin_amdgcn_fdot2)
  return __builtin_amdgcn_fdot2(__builtin_bit_cast(half2_t, w),
                                __builtin_bit_cast(half2_t, x), c, false);
#else
  half2_t wh = __builtin_bit_cast(half2_t, w);
  half2_t xh = __builtin_bit_cast(half2_t, x);
  return c + (float)wh.x * (float)xh.x + (float)wh.y * (float)xh.y;
#endif
}

// XOR swizzle on 16B granules: lanes read granule 4t+q (stride 64B) -> would be
// 8-way bank conflict; xor of bits[2:0] with bits[5:3] makes it <=2-way (free).
__device__ __forceinline__ uint32_t swz(uint32_t g) { return g ^ ((g >> 3) & 7u); }

__global__ __launch_bounds__(256, 2) void fp4gemv(
    const float* __restrict__ x, const uint32_t* __restrict__ qw,
    const float* __restrict__ am, const float* __restrict__ bias,
    float* __restrict__ out) {
  // x staged as packed-f16 column pairs: granule p (cols 2p,2p+1) =
  // 4 dwords, dword i = half2(x[i][2p], x[i][2p+1]).  4096 granules = 64 KB.
  __shared__ uint32_t xs[4096 * 4];

  // ---- stage x -> LDS (each block reads x once: 128 KB, L2/L3-resident) ----
#pragma unroll 4
  for (int it = 0; it < 16; ++it) {
    int p = threadIdx.x + it * 256;
    float2 v0 = *(const float2*)(x + 0 * NDIM + 2 * p);
    float2 v1 = *(const float2*)(x + 1 * NDIM + 2 * p);
    float2 v2 = *(const float2*)(x + 2 * NDIM + 2 * p);
    float2 v3 = *(const float2*)(x + 3 * NDIM + 2 * p);
    union { _Float16 h[2]; uint32_t u; } c0, c1, c2, c3;
    c0.h[0] = (_Float16)v0.x; c0.h[1] = (_Float16)v0.y;
    c1.h[0] = (_Float16)v1.x; c1.h[1] = (_Float16)v1.y;
    c2.h[0] = (_Float16)v2.x; c2.h[1] = (_Float16)v2.y;
    c3.h[0] = (_Float16)v3.x; c3.h[1] = (_Float16)v3.y;
    uint4 w; w.x = c0.u; w.y = c1.u; w.z = c2.u; w.w = c3.u;
    *(uint4*)&xs[swz((uint32_t)p) * 4] = w;
  }
  __syncthreads();

  // ---- main: wave handles 4 rows (lane>>4), 16 lanes stride the columns ----
  const int lane = threadIdx.x & 63;
  const int wv   = threadIdx.x >> 6;
  const int t    = lane & 15;       // column slot within row group
  const int g    = lane >> 4;       // row within group
  const int m    = blockIdx.x * ROWS_PER_BLOCK + wv * 4 + g;

  const uint4* qrow  = (const uint4*)(qw + (size_t)m * QPR);   // 1024 uint4/row
  const float* abrow = am + (size_t)m * ABPR + (t >> 3);

  float a0 = 0.f, a1 = 0.f, a2 = 0.f, a3 = 0.f;

  // 2-deep register prefetch of qweight (coalesced 256B per 16-lane group)
  uint4 qA = qrow[t];        float sA = abrow[0];
  uint4 qB = qrow[t + 16];   float sB = abrow[2];

#pragma unroll 2
  for (int k = 0; k < NITER; ++k) {
    const int kn = (k + 2) & 63;
    uint4 qC = qrow[t + 16 * kn];
    float sC = abrow[2 * kn];

    // decode 4 bytes -> 8 f16 weights (4 packed pairs)
    uint32_t h0 = dec_pair(qA.x);
    uint32_t h1 = dec_pair(qA.y);
    uint32_t h2 = dec_pair(qA.z);
    uint32_t h3 = dec_pair(qA.w);

    // x granules for this lane's 8 columns (all within one absmax block)
    const int j0 = 4 * t + 64 * k;
    uint4 x0 = *(const uint4*)&xs[swz((uint32_t)(j0 + 0)) * 4];
    uint4 x1 = *(const uint4*)&xs[swz((uint32_t)(j0 + 1)) * 4];
    uint4 x2 = *(const uint4*)&xs[swz((uint32_t)(j0 + 2)) * 4];
    uint4 x3 = *(const uint4*)&xs[swz((uint32_t)(j0 + 3)) * 4];

    float s0, s1, s2, s3;
    s0 = fdot2(h0, x0.x, 0.f); s0 = fdot2(h1, x1.x, s0);
    s0 = fdot2(h2, x2.x, s0);  s0 = fdot2(h3, x3.x, s0);
    s1 = fdot2(h0, x0.y, 0.f); s1 = fdot2(h1, x1.y, s1);
    s1 = fdot2(h2, x2.y, s1);  s1 = fdot2(h3, x3.y, s1);
    s2 = fdot2(h0, x0.z, 0.f); s2 = fdot2(h1, x1.z, s2);
    s2 = fdot2(h2, x2.z, s2);  s2 = fdot2(h3, x3.z, s2);
    s3 = fdot2(h0, x0.w, 0.f); s3 = fdot2(h1, x1.w, s3);
    s3 = fdot2(h2, x2.w, s3);  s3 = fdot2(h3, x3.w, s3);

    // fold per-64-col absmax once per iteration (8 cols, one block)
    a0 = fmaf(sA, s0, a0); a1 = fmaf(sA, s1, a1);
    a2 = fmaf(sA, s2, a2); a3 = fmaf(sA, s3, a3);

    qA = qB; sA = sB; qB = qC; sB = sC;
  }

  // reduce across the 16 column-slot lanes of each row group
#pragma unroll
  for (int off = 8; off > 0; off >>= 1) {
    a0 += __shfl_xor(a0, off);
    a1 += __shfl_xor(a1, off);
    a2 += __shfl_xor(a2, off);
    a3 += __shfl_xor(a3, off);
  }
  if (t == 0) {
    float b = bias[m];
    out[0 * MDIM + m] = a0 + b;
    out[1 * MDIM + m] = a1 + b;
    out[2 * MDIM + m] = a2 + b;
    out[3 * MDIM + m] = a3 + b;
  }
}

extern "C" void kernel_launch(void* const* d_in, const int* in_sizes, int n_in,
                              void* d_out, int out_size, void* d_ws, size_t ws_size,
                              hipStream_t stream) {
  const float*    x    = (const float*)d_in[0];
  const uint32_t* qwp  = (const uint32_t*)d_in[1];   // int32 values 0..255
  const float*    am   = (const float*)d_in[2];
  // d_in[3] = code (fixed FP4 codebook, folded into f16bits())
  const float*    bias = (const float*)d_in[4];
  float*          out  = (float*)d_out;

  fp4gemv<<<dim3(MDIM / ROWS_PER_BLOCK), dim3(256), 0, stream>>>(
      x, qwp, am, bias, out);
}

// Round 3
// 202.731 us; speedup vs baseline: 1.0043x; 1.0043x over previous
//
#include <hip/hip_runtime.h>
#include <cstdint>

#define MDIM 8192
#define NDIM 8192
#define QPR  (NDIM / 2)     // packed int32 entries per row = 4096
#define ABPR (NDIM / 64)    // absmax blocks per row = 128
#define ROWS_PER_BLOCK 16
#define HGRAN 2048          // column-pair granules per half-block (4096 cols)
#define NITER 32            // 16 lanes x 4 int32 x 32 iters = 2048 int32 = half row

typedef _Float16 half2_t __attribute__((ext_vector_type(2)));
typedef uint32_t u32x4   __attribute__((ext_vector_type(4)));

// fp4 bitsandbytes codebook entry -> IEEE f16 bits, pure VALU.
// magnitudes k=0..7: {0, 1/192, 2/3, 1, 1/3, 1/2, 1/6, 1/4}
// f16 hi-byte table (byte k): 0x00,0x1D,0x39,0x3C,0x35,0x38,0x31,0x34
// low mantissa byte is 0x55 exactly when hi-byte is odd; sign = idx bit3.
__device__ __forceinline__ uint32_t f16bits(uint32_t idx) {
  uint32_t k  = idx & 7u;
  uint32_t hb = (uint32_t)(0x343138353C391D00ull >> (k * 8)) & 0xFFu;
  uint32_t lb = (0u - (hb & 1u)) & 0x55u;
  return (hb << 8) | lb | ((idx & 8u) << 12);
}

// packed byte -> half2 (element0 = hi nibble = even column)
__device__ __forceinline__ uint32_t dec_pair(uint32_t b) {
  return f16bits((b >> 4) & 15u) | (f16bits(b & 15u) << 16);
}

__device__ __forceinline__ float fdot2(uint32_t w, uint32_t x, float c) {
#if __has_builtin(__builtin_amdgcn_fdot2)
  return __builtin_amdgcn_fdot2(__builtin_bit_cast(half2_t, w),
                                __builtin_bit_cast(half2_t, x), c, false);
#else
  half2_t wh = __builtin_bit_cast(half2_t, w);
  half2_t xh = __builtin_bit_cast(half2_t, x);
  return c + (float)wh.x * (float)wh.x + (float)wh.y * (float)xh.y;
#endif
}

__device__ __forceinline__ u32x4 ntload(const u32x4* p) {
#if __has_builtin(__builtin_nontemporal_load)
  return __builtin_nontemporal_load(p);
#else
  return *p;
#endif
}

// XOR swizzle on 16B granules: lanes hit granules 4t+c (stride 64B) -> 8-way
// bank conflict unswizzled; xor bits[2:0] ^= bits[5:3] makes it <=2-way (free).
__device__ __forceinline__ uint32_t swz(uint32_t g) { return g ^ ((g >> 3) & 7u); }

// d_out is poisoned 0xAA; seed it with bias so the main kernel can atomicAdd.
__global__ void bias_init(const float* __restrict__ bias, float* __restrict__ out) {
  int i = blockIdx.x * 256 + threadIdx.x;          // 32768 threads
  out[i] = bias[i & (MDIM - 1)];
}

__global__ __launch_bounds__(256, 4) void fp4gemv(
    const float* __restrict__ x, const uint32_t* __restrict__ qw,
    const float* __restrict__ am, const float* __restrict__ bias,
    float* __restrict__ out) {
  // x staged as packed-f16 column pairs for this block's half of the columns:
  // granule p = 4 dwords, dword i = half2(x[i][c], x[i][c+1]).  32 KB.
  __shared__ uint32_t xs[HGRAN * 4];

  const int half = blockIdx.x & 1;       // which half of the columns
  const int mblk = blockIdx.x >> 1;      // which 16-row group

  // ---- stage x -> LDS (64 KB of x per block; L2/L3-resident) ----
#pragma unroll 4
  for (int it = 0; it < 8; ++it) {
    int p = threadIdx.x + it * 256;                 // local granule 0..2047
    int c = 2 * (half * HGRAN + p);                 // global column
    float2 v0 = *(const float2*)(x + 0 * NDIM + c);
    float2 v1 = *(const float2*)(x + 1 * NDIM + c);
    float2 v2 = *(const float2*)(x + 2 * NDIM + c);
    float2 v3 = *(const float2*)(x + 3 * NDIM + c);
    union { _Float16 h[2]; uint32_t u; } c0, c1, c2, c3;
    c0.h[0] = (_Float16)v0.x; c0.h[1] = (_Float16)v0.y;
    c1.h[0] = (_Float16)v1.x; c1.h[1] = (_Float16)v1.y;
    c2.h[0] = (_Float16)v2.x; c2.h[1] = (_Float16)v2.y;
    c3.h[0] = (_Float16)v3.x; c3.h[1] = (_Float16)v3.y;
    uint4 w; w.x = c0.u; w.y = c1.u; w.z = c2.u; w.w = c3.u;
    *(uint4*)&xs[swz((uint32_t)p) * 4] = w;
  }
  __syncthreads();

  // ---- main: wave = 4 rows x 16 column-slot lanes ----
  const int lane = threadIdx.x & 63;
  const int wv   = threadIdx.x >> 6;
  const int t    = lane & 15;
  const int g    = lane >> 4;
  const int m    = mblk * ROWS_PER_BLOCK + wv * 4 + g;

  const u32x4* qrow  = (const u32x4*)(qw + (size_t)m * QPR + half * 2048);
  const float* abrow = am + (size_t)m * ABPR + half * 64 + (t >> 3);

  float a0 = 0.f, a1 = 0.f, a2 = 0.f, a3 = 0.f;

  // depth-4 register ring prefetch (each load = 256B coalesced per row group)
  u32x4 q[4]; float s[4];
#pragma unroll
  for (int i = 0; i < 4; ++i) {
    q[i] = ntload(&qrow[t + 16 * i]);
    s[i] = abrow[2 * i];
  }

#pragma unroll 4
  for (int k = 0; k < NITER; ++k) {
    const int r = k & 3;
    u32x4 qA = q[r];  float sA = s[r];
    int kn = k + 4; if (kn >= NITER) kn -= NITER;   // wrap: re-reads are L2 hits
    q[r] = ntload(&qrow[t + 16 * kn]);
    s[r] = abrow[2 * kn];

    uint32_t h0 = dec_pair(qA.x);
    uint32_t h1 = dec_pair(qA.y);
    uint32_t h2 = dec_pair(qA.z);
    uint32_t h3 = dec_pair(qA.w);

    const int j0 = 4 * t + 64 * k;                  // local granule base
    uint4 x0 = *(const uint4*)&xs[swz((uint32_t)(j0 + 0)) * 4];
    uint4 x1 = *(const uint4*)&xs[swz((uint32_t)(j0 + 1)) * 4];
    uint4 x2 = *(const uint4*)&xs[swz((uint32_t)(j0 + 2)) * 4];
    uint4 x3 = *(const uint4*)&xs[swz((uint32_t)(j0 + 3)) * 4];

    float s0, s1, s2, s3;
    s0 = fdot2(h0, x0.x, 0.f); s0 = fdot2(h1, x1.x, s0);
    s0 = fdot2(h2, x2.x, s0);  s0 = fdot2(h3, x3.x, s0);
    s1 = fdot2(h0, x0.y, 0.f); s1 = fdot2(h1, x1.y, s1);
    s1 = fdot2(h2, x2.y, s1);  s1 = fdot2(h3, x3.y, s1);
    s2 = fdot2(h0, x0.z, 0.f); s2 = fdot2(h1, x1.z, s2);
    s2 = fdot2(h2, x2.z, s2);  s2 = fdot2(h3, x3.z, s2);
    s3 = fdot2(h0, x0.w, 0.f); s3 = fdot2(h1, x1.w, s3);
    s3 = fdot2(h2, x2.w, s3);  s3 = fdot2(h3, x3.w, s3);

    // per-64-col absmax folded once per iteration (8 cols in one block)
    a0 = fmaf(sA, s0, a0); a1 = fmaf(sA, s1, a1);
    a2 = fmaf(sA, s2, a2); a3 = fmaf(sA, s3, a3);
  }

  // reduce across the 16 column-slot lanes of each row group
#pragma unroll
  for (int off = 8; off > 0; off >>= 1) {
    a0 += __shfl_xor(a0, off);
    a1 += __shfl_xor(a1, off);
    a2 += __shfl_xor(a2, off);
    a3 += __shfl_xor(a3, off);
  }
  if (t == 0) {
    atomicAdd(&out[0 * MDIM + m], a0);
    atomicAdd(&out[1 * MDIM + m], a1);
    atomicAdd(&out[2 * MDIM + m], a2);
    atomicAdd(&out[3 * MDIM + m], a3);
  }
}

extern "C" void kernel_launch(void* const* d_in, const int* in_sizes, int n_in,
                              void* d_out, int out_size, void* d_ws, size_t ws_size,
                              hipStream_t stream) {
  const float*    x    = (const float*)d_in[0];
  const uint32_t* qwp  = (const uint32_t*)d_in[1];   // int32 values 0..255
  const float*    am   = (const float*)d_in[2];
  // d_in[3] = code (fixed FP4 codebook, folded into f16bits())
  const float*    bias = (const float*)d_in[4];
  float*          out  = (float*)d_out;

  bias_init<<<dim3((4 * MDIM) / 256), dim3(256), 0, stream>>>(bias, out);
  fp4gemv<<<dim3((MDIM / ROWS_PER_BLOCK) * 2), dim3(256), 0, stream>>>(
      x, qwp, am, bias, out);
}